// Round 2
// baseline (3764.467 us; speedup 1.0000x reference)
//
#include <hip/hip_runtime.h>
#include <math.h>

// Problem constants
#define Bq 8
#define Tt 128
#define Ee 384
#define Hh 768
#define Ll 9
#define GATE 1536   // 4*E

// ---------------------------------------------------------------------------
// Generic f32 GEMM: C[m,n] = sum_k A[m,k]*Bw[n,k] + b1[n] + b2[n] + bbn[m>>7][n]
// A row-major (M,K), Bw row-major (N,K), C row-major (M,N). grid.z batches via
// strides. BM=BN=128, BK=16, 256 threads, 8x8 microtile.
// ---------------------------------------------------------------------------
#define BM 128
#define BN 128
#define BKk 16

__global__ __launch_bounds__(256) void k_gemm(
    const float* __restrict__ A, const float* __restrict__ Bw, float* __restrict__ C,
    int M, int N, int K,
    long sAz, long sBz, long sCz,
    const float* __restrict__ b1, const float* __restrict__ b2, long sbz,
    const float* __restrict__ bbn)
{
    int z = blockIdx.z;
    A += (long)z * sAz;
    Bw += (long)z * sBz;
    C += (long)z * sCz;
    const float* bb1 = b1 ? b1 + (long)z * sbz : nullptr;
    const float* bb2 = b2 ? b2 + (long)z * sbz : nullptr;

    int n0 = blockIdx.x * BN;
    int m0 = blockIdx.y * BM;
    int tid = threadIdx.x;

    __shared__ float As[BKk][BM];
    __shared__ float Bs[BKk][BN];

    int lr = tid >> 2;          // 0..63
    int lc = (tid & 3) * 4;     // 0,4,8,12
    int tx = tid & 15;
    int ty = tid >> 4;

    float acc[8][8];
#pragma unroll
    for (int i = 0; i < 8; ++i)
#pragma unroll
        for (int j = 0; j < 8; ++j) acc[i][j] = 0.f;

    for (int k0 = 0; k0 < K; k0 += BKk) {
        float4 a0 = *(const float4*)&A[(long)(m0 + lr) * K + k0 + lc];
        float4 a1 = *(const float4*)&A[(long)(m0 + lr + 64) * K + k0 + lc];
        float4 w0 = *(const float4*)&Bw[(long)(n0 + lr) * K + k0 + lc];
        float4 w1 = *(const float4*)&Bw[(long)(n0 + lr + 64) * K + k0 + lc];
        __syncthreads();
        As[lc + 0][lr] = a0.x; As[lc + 1][lr] = a0.y; As[lc + 2][lr] = a0.z; As[lc + 3][lr] = a0.w;
        As[lc + 0][lr + 64] = a1.x; As[lc + 1][lr + 64] = a1.y; As[lc + 2][lr + 64] = a1.z; As[lc + 3][lr + 64] = a1.w;
        Bs[lc + 0][lr] = w0.x; Bs[lc + 1][lr] = w0.y; Bs[lc + 2][lr] = w0.z; Bs[lc + 3][lr] = w0.w;
        Bs[lc + 0][lr + 64] = w1.x; Bs[lc + 1][lr + 64] = w1.y; Bs[lc + 2][lr + 64] = w1.z; Bs[lc + 3][lr + 64] = w1.w;
        __syncthreads();
#pragma unroll
        for (int kk = 0; kk < BKk; ++kk) {
            float av[8], bv[8];
            *(float4*)&av[0] = *(float4*)&As[kk][ty * 8];
            *(float4*)&av[4] = *(float4*)&As[kk][ty * 8 + 4];
            *(float4*)&bv[0] = *(float4*)&Bs[kk][tx * 8];
            *(float4*)&bv[4] = *(float4*)&Bs[kk][tx * 8 + 4];
#pragma unroll
            for (int i = 0; i < 8; ++i)
#pragma unroll
                for (int j = 0; j < 8; ++j)
                    acc[i][j] = fmaf(av[i], bv[j], acc[i][j]);
        }
    }

#pragma unroll
    for (int i = 0; i < 8; ++i) {
        long m = m0 + ty * 8 + i;
#pragma unroll
        for (int j = 0; j < 8; ++j) {
            int n = n0 + tx * 8 + j;
            float val = acc[i][j];
            if (bb1) val += bb1[n];
            if (bb2) val += bb2[n];
            if (bbn) val += bbn[(m >> 7) * (long)N + n];
            C[m * N + n] = val;
        }
    }
}

// ---------------------------------------------------------------------------
// Manual grid barrier for a group of `nb` co-resident blocks sharing counter
// `ctr` (device-scope atomics + agent fences; cumulative target per iter).
// ---------------------------------------------------------------------------
__device__ __forceinline__ void gbar(unsigned* ctr, unsigned it, unsigned nb)
{
    __syncthreads();
    if (threadIdx.x == 0) {
        __threadfence();   // release: make my Yout stores visible device-wide
        __hip_atomic_fetch_add(ctr, 1u, __ATOMIC_RELEASE, __HIP_MEMORY_SCOPE_AGENT);
        unsigned tgt = (it + 1u) * nb;
        while (__hip_atomic_load(ctr, __ATOMIC_ACQUIRE, __HIP_MEMORY_SCOPE_AGENT) < tgt) {
            __builtin_amdgcn_s_sleep(1);
        }
        __threadfence();   // acquire: invalidate stale cache lines
    }
    __syncthreads();
}

// ---------------------------------------------------------------------------
// LSTM recurrence for one layer (both directions), NORMAL launch, 32 blocks.
// d = bid>>4, slice s = bid&15. Blocks of a direction sync among themselves
// via gbar (16 arrivals); fwd/bwd are independent chains.
// Each block owns 96 gate rows (24 h rows x 4 gates) of W_hh in registers.
// h exchanged via Yout global. c in registers.
// G: [2][B*T][1536] precomputed input projections (+biases).
// Yout: [B][T][768] (fwd cols 0:384, bwd cols 384:768) = layer output.
// ---------------------------------------------------------------------------
__global__ __launch_bounds__(256, 1) void k_lstm(
    const float* __restrict__ G, const float* __restrict__ Whh, float* Yout,
    unsigned* barbase)
{
    int bid = blockIdx.x;
    int d = bid >> 4;
    int s = bid & 15;
    int tid = threadIdx.x;
    int kq = tid >> 5;          // 0..7  (k-range of 48)
    int rg = tid & 31;          // 0..31 (3 rows each)
    int kq48 = kq * 48;
    unsigned* ctr = barbase + d * 16;   // one cacheline per direction

    __shared__ float hl[8 * 384];       // h_prev for all batches of this dir
    __shared__ float part[8 * 776];     // partials: [kq][b(stride 97)][row 0..95]

    // Load W slice into registers
    float W_[3][48];
    const float* Wd = Whh + (long)d * GATE * Ee;
#pragma unroll
    for (int r = 0; r < 3; ++r) {
        int rl = rg * 3 + r;
        int g = rl / 24, rr = rl % 24;
        const float* src = Wd + (long)(g * Ee + s * 24 + rr) * Ee + kq48;
#pragma unroll
        for (int k4 = 0; k4 < 12; ++k4) {
            float4 w = *(const float4*)&src[k4 * 4];
            W_[r][k4 * 4 + 0] = w.x;
            W_[r][k4 * 4 + 1] = w.y;
            W_[r][k4 * 4 + 2] = w.z;
            W_[r][k4 * 4 + 3] = w.w;
        }
    }

    float cst = 0.f;                  // cell state for update thread
    int ub = tid / 24, ur = tid % 24; // update thread -> (batch, h-row)
    bool upd = tid < 192;

    for (int it = 0; it < 128; ++it) {
        int tt = d ? (127 - it) : it;
        int tp = d ? (tt + 1) : (tt - 1);

        // stage h_{prev} for all 8 batches
        if (it == 0) {
            for (int ii = 0; ii < 12; ++ii) hl[tid + 256 * ii] = 0.f;
        } else {
            for (int ii = 0; ii < 12; ++ii) {
                int i = tid + 256 * ii;
                int b = i / 384, k = i - b * 384;
                hl[i] = Yout[((long)(b * Tt + tp)) * Hh + d * Ee + k];
            }
        }
        __syncthreads();

        float acc[8][3];
#pragma unroll
        for (int b = 0; b < 8; ++b)
#pragma unroll
            for (int r = 0; r < 3; ++r) acc[b][r] = 0.f;

#pragma unroll
        for (int k4 = 0; k4 < 12; ++k4) {
#pragma unroll
            for (int b = 0; b < 8; ++b) {
                float4 hv = *(const float4*)&hl[b * 384 + kq48 + k4 * 4];
#pragma unroll
                for (int r = 0; r < 3; ++r) {
                    acc[b][r] = fmaf(W_[r][k4 * 4 + 0], hv.x, acc[b][r]);
                    acc[b][r] = fmaf(W_[r][k4 * 4 + 1], hv.y, acc[b][r]);
                    acc[b][r] = fmaf(W_[r][k4 * 4 + 2], hv.z, acc[b][r]);
                    acc[b][r] = fmaf(W_[r][k4 * 4 + 3], hv.w, acc[b][r]);
                }
            }
        }

        // write partials
#pragma unroll
        for (int b = 0; b < 8; ++b)
#pragma unroll
            for (int r = 0; r < 3; ++r)
                part[kq * 776 + b * 97 + rg * 3 + r] = acc[b][r];
        __syncthreads();

        if (upd) {
            float gt[4];
#pragma unroll
            for (int g = 0; g < 4; ++g) {
                int rl = g * 24 + ur;
                float sum = G[((long)d * 1024 + ub * Tt + tt) * GATE + g * Ee + s * 24 + ur];
#pragma unroll
                for (int q = 0; q < 8; ++q) sum += part[q * 776 + ub * 97 + rl];
                gt[g] = sum;
            }
            float ig = 1.f / (1.f + expf(-gt[0]));
            float fg = 1.f / (1.f + expf(-gt[1]));
            float gg = tanhf(gt[2]);
            float og = 1.f / (1.f + expf(-gt[3]));
            cst = fg * cst + ig * gg;
            float h = og * tanhf(cst);
            Yout[((long)(ub * Tt + tt)) * Hh + d * Ee + s * 24 + ur] = h;
        }
        if (it != 127) gbar(ctr, (unsigned)it, 16u);
    }
}

// ---------------------------------------------------------------------------
// p_term[b][n] = sum_k hs[b, qid[b], k] * W_p[n,k]
// ---------------------------------------------------------------------------
__global__ __launch_bounds__(256) void k_pterm(
    const float* __restrict__ hs, const int* __restrict__ qids,
    const float* __restrict__ Wp, float* __restrict__ pterm)
{
    int b = blockIdx.x;
    int tid = threadIdx.x;
    int qid = qids[b];
    __shared__ float hp[Hh];
    for (int i = tid; i < Hh; i += 256) hp[i] = hs[((long)(b * Tt + qid)) * Hh + i];
    __syncthreads();
    int w = tid >> 6, lane = tid & 63;
    for (int n = w; n < Hh; n += 4) {
        float p = 0.f;
        for (int k = lane; k < Hh; k += 64) p += hp[k] * Wp[(long)n * Hh + k];
#pragma unroll
        for (int o = 32; o; o >>= 1) p += __shfl_down(p, o);
        if (lane == 0) pterm[b * Hh + n] = p;
    }
}

// ---------------------------------------------------------------------------
// Fused attention per (b,t): scores -> softmax -> c -> logits. Stores a_mat
// (for pooling) and logits (for viterbi).
// ---------------------------------------------------------------------------
__global__ __launch_bounds__(256) void k_attn(
    const float* __restrict__ hs, const float* __restrict__ A1, const float* __restrict__ A2,
    const float* __restrict__ v, const float* __restrict__ Wclf,
    float* __restrict__ a_mat, float* __restrict__ logits)
{
    int b = blockIdx.x >> 7, t = blockIdx.x & 127;
    int tid = threadIdx.x;
    long bt = (long)(b * Tt + t);

    __shared__ float a2r[Hh], vr[Hh], hsr[Hh], crow[Hh];
    __shared__ float sc[128], tmp[256], red2[2];

    for (int i = tid; i < Hh; i += 256) {
        a2r[i] = A2[bt * Hh + i];
        vr[i] = v[i];
        hsr[i] = hs[bt * Hh + i];
    }
    __syncthreads();

    // scores: 2 threads per s (each 384 of 768)
    {
        int sid = tid >> 1, half = tid & 1;
        float p = 0.f;
        const float* A1r = &A1[((long)(b * Tt + sid)) * Hh + half * 384];
        const float* a2h = &a2r[half * 384];
        const float* vh = &vr[half * 384];
        for (int k = 0; k < 384; k += 4) {
            float4 z = *(const float4*)&A1r[k];
            p += vh[k + 0] * tanhf(z.x + a2h[k + 0]);
            p += vh[k + 1] * tanhf(z.y + a2h[k + 1]);
            p += vh[k + 2] * tanhf(z.z + a2h[k + 2]);
            p += vh[k + 3] * tanhf(z.w + a2h[k + 3]);
        }
        tmp[tid] = p;
    }
    __syncthreads();
    if (tid < 128) sc[tid] = tmp[2 * tid] + tmp[2 * tid + 1];
    __syncthreads();

    // softmax over s
    if (tid < 64) {
        float m = fmaxf(sc[tid], sc[tid + 64]);
#pragma unroll
        for (int o = 32; o; o >>= 1) m = fmaxf(m, __shfl_down(m, o));
        if (tid == 0) red2[0] = m;
    }
    __syncthreads();
    float mx = red2[0];
    if (tid < 128) sc[tid] = expf(sc[tid] - mx);
    __syncthreads();
    if (tid < 64) {
        float sm = sc[tid] + sc[tid + 64];
#pragma unroll
        for (int o = 32; o; o >>= 1) sm += __shfl_down(sm, o);
        if (tid == 0) red2[1] = sm;
    }
    __syncthreads();
    float inv = 1.f / red2[1];
    if (tid < 128) {
        sc[tid] *= inv;
        a_mat[bt * 128 + tid] = sc[tid];
    }
    __syncthreads();

    // c[b,t,:] = sum_s a_s * hs[b,s,:]
    float c0 = 0.f, c1 = 0.f, c2 = 0.f;
    for (int s2 = 0; s2 < 128; ++s2) {
        float as = sc[s2];
        const float* hrow = &hs[((long)(b * Tt + s2)) * Hh];
        c0 = fmaf(as, hrow[tid], c0);
        c1 = fmaf(as, hrow[tid + 256], c1);
        c2 = fmaf(as, hrow[tid + 512], c2);
    }
    crow[tid] = c0; crow[tid + 256] = c1; crow[tid + 512] = c2;
    __syncthreads();

    // logits[b,t,l] = [hs | c] . Wclf[l]
    for (int l = 0; l < Ll; ++l) {
        float p = 0.f;
        for (int h = tid; h < 2 * Hh; h += 256) {
            float u = (h < Hh) ? hsr[h] : crow[h - Hh];
            p = fmaf(u, Wclf[l * 2 * Hh + h], p);
        }
#pragma unroll
        for (int o = 32; o; o >>= 1) p += __shfl_down(p, o);
        if ((tid & 63) == 0) tmp[tid >> 6] = p;
        __syncthreads();
        if (tid == 0) logits[bt * Ll + l] = tmp[0] + tmp[1] + tmp[2] + tmp[3];
        __syncthreads();
    }
}

// ---------------------------------------------------------------------------
// a_t[b][s] = (sum_t a[b,t,s]) / (sum_s sum_t a[b,t,s])
// ---------------------------------------------------------------------------
__global__ void k_norm(const float* __restrict__ a_mat, float* __restrict__ a_t)
{
    int b = blockIdx.x;
    int s = threadIdx.x; // 128
    float sum = 0.f;
    for (int t = 0; t < Tt; ++t) sum += a_mat[((long)(b * Tt + t)) * 128 + s];
    __shared__ float pool[128];
    __shared__ float tot;
    pool[s] = sum;
    __syncthreads();
    if (s < 64) {
        float v2 = pool[s] + pool[s + 64];
#pragma unroll
        for (int o = 32; o; o >>= 1) v2 += __shfl_down(v2, o);
        if (s == 0) tot = v2;
    }
    __syncthreads();
    float tv = tot;
    a_t[b * 128 + s] = (tv != 0.f) ? pool[s] / tv : 0.f;
}

// ---------------------------------------------------------------------------
// Viterbi (L=9). One block. Strict-> argmax to match jnp.argmax first-max.
// ---------------------------------------------------------------------------
__global__ void k_viterbi(const float* __restrict__ logits, const float* __restrict__ trans,
                          const float* __restrict__ start, const float* __restrict__ endw,
                          float* __restrict__ out)
{
    __shared__ float sc[2][72];
    __shared__ unsigned char ptrs[127][72];
    __shared__ unsigned char tags[8][128];
    int tid = threadIdx.x;
    int b = tid / 9, j = tid % 9;
    bool act = tid < 72;
    if (act) sc[0][b * 9 + j] = start[j] + logits[(b * Tt + 0) * Ll + j];
    __syncthreads();
    for (int t = 1; t < Tt; ++t) {
        int cur = t & 1, prv = cur ^ 1;
        if (act) {
            float best = -1e30f; int bi = 0;
#pragma unroll
            for (int i = 0; i < 9; ++i) {
                float vv = sc[prv][b * 9 + i] + trans[i * 9 + j];
                if (vv > best) { best = vv; bi = i; }
            }
            sc[cur][b * 9 + j] = best + logits[(b * Tt + t) * Ll + j];
            ptrs[t - 1][b * 9 + j] = (unsigned char)bi;
        }
        __syncthreads();
    }
    if (act && j == 0) {
        float best = -1e30f; int bj = 0;
#pragma unroll
        for (int jj = 0; jj < 9; ++jj) {
            float vv = sc[1][b * 9 + jj] + endw[jj];
            if (vv > best) { best = vv; bj = jj; }
        }
        int tg = bj;
        tags[b][127] = (unsigned char)tg;
        for (int t = 127; t >= 1; --t) {
            tg = ptrs[t - 1][b * 9 + tg];
            tags[b][t - 1] = (unsigned char)tg;
        }
    }
    __syncthreads();
    for (int i = tid; i < Bq * Tt * Ll; i += blockDim.x) {
        int l = i % 9;
        int btx = i / 9;
        int tt2 = btx % Tt;
        int bb = btx / Tt;
        out[i] = (tags[bb][tt2] == l) ? 10.f : -1.f;
    }
}

// ---------------------------------------------------------------------------
extern "C" void kernel_launch(void* const* d_in, const int* in_sizes, int n_in,
                              void* d_out, int out_size, void* d_ws, size_t ws_size,
                              hipStream_t stream)
{
    const float* embeds   = (const float*)d_in[0];
    const int*   qids     = (const int*)d_in[1];
    const float* w_ih_l0  = (const float*)d_in[2];
    const float* w_ih_rest= (const float*)d_in[3];
    const float* w_hh     = (const float*)d_in[4];
    const float* b_ih     = (const float*)d_in[5];
    const float* b_hh     = (const float*)d_in[6];
    const float* W_H      = (const float*)d_in[7];
    const float* W_p      = (const float*)d_in[8];
    const float* W_h      = (const float*)d_in[9];
    const float* vvec     = (const float*)d_in[10];
    const float* W_clf    = (const float*)d_in[11];
    const float* trans    = (const float*)d_in[12];
    const float* cstart   = (const float*)d_in[13];
    const float* cend     = (const float*)d_in[14];

    float* out = (float*)d_out;
    float* vit_out = out;                          // 8*128*9   = 9216
    float* hs      = out + 9216;                   // 8*128*768 = 786432
    float* a_t     = out + 9216 + 786432;          // 8*128     = 1024

    // Workspace overlay (peak 18.0 MB + barrier cachelines):
    //  phase A (LSTM):   G [3145728] | Y0 [786432] | Y1 [786432] | bar
    //  phase B (attn):   A1,A2,pterm,a_mat,logits all inside G's region
    float* ws = (float*)d_ws;
    float* G      = ws;                  // 3145728 floats
    float* Y0     = ws + 3145728;        // 786432
    float* Y1     = Y0 + 786432;         // 786432
    unsigned* bar = (unsigned*)(ws + 3145728 + 2 * 786432);  // 6*16 u32
    float* A1     = ws;                  // reuses G (dead after last lstm)
    float* A2     = A1 + 786432;
    float* pterm  = A2 + 786432;         // 6144
    float* a_mat  = pterm + 6144;        // 131072
    float* logits = a_mat + 131072;      // 9216  (ends at 2505728 < 3145728)

    dim3 blk(256);

    // Reset barrier counters every call (deterministic, capture-safe).
    hipMemsetAsync(bar, 0, 6 * 16 * sizeof(unsigned), stream);

    // ---- Layer 0 ----
    k_gemm<<<dim3(GATE / BN, 1024 / BM, 2), blk, 0, stream>>>(
        embeds, w_ih_l0, G, 1024, GATE, Ee,
        0L, (long)GATE * Ee, (long)1024 * GATE,
        b_ih, b_hh, (long)GATE, nullptr);
    k_lstm<<<dim3(32), blk, 0, stream>>>(G, w_hh, Y0, bar);

    // ---- Layer 1 ----
    k_gemm<<<dim3(GATE / BN, 1024 / BM, 2), blk, 0, stream>>>(
        Y0, w_ih_rest, G, 1024, GATE, Hh,
        0L, (long)GATE * Hh, (long)1024 * GATE,
        b_ih + 2 * GATE, b_hh + 2 * GATE, (long)GATE, nullptr);
    k_lstm<<<dim3(32), blk, 0, stream>>>(G, w_hh + (long)2 * GATE * Ee, Y1, bar + 32);

    // ---- Layer 2 ----
    k_gemm<<<dim3(GATE / BN, 1024 / BM, 2), blk, 0, stream>>>(
        Y1, w_ih_rest + (long)2 * GATE * Hh, G, 1024, GATE, Hh,
        0L, (long)GATE * Hh, (long)1024 * GATE,
        b_ih + 4 * GATE, b_hh + 4 * GATE, (long)GATE, nullptr);
    k_lstm<<<dim3(32), blk, 0, stream>>>(G, w_hh + (long)4 * GATE * Ee, hs, bar + 64);

    // ---- Attention precompute ----
    k_pterm<<<dim3(8), blk, 0, stream>>>(hs, qids, W_p, pterm);
    k_gemm<<<dim3(Hh / BN, 1024 / BM, 1), blk, 0, stream>>>(
        hs, W_H, A1, 1024, Hh, Hh, 0L, 0L, 0L, nullptr, nullptr, 0L, nullptr);
    k_gemm<<<dim3(Hh / BN, 1024 / BM, 1), blk, 0, stream>>>(
        hs, W_h, A2, 1024, Hh, Hh, 0L, 0L, 0L, nullptr, nullptr, 0L, pterm);

    // ---- Fused attention + logits ----
    k_attn<<<dim3(1024), blk, 0, stream>>>(hs, A1, A2, vvec, W_clf, a_mat, logits);

    // ---- Pooled attention norm -> a_t ----
    k_norm<<<dim3(8), dim3(128), 0, stream>>>(a_mat, a_t);

    // ---- Viterbi -> vit_logits ----
    k_viterbi<<<dim3(1), dim3(128), 0, stream>>>(logits, trans, cstart, cend, vit_out);
}

// Round 3
// 2660.468 us; speedup vs baseline: 1.4150x; 1.4150x over previous
//
#include <hip/hip_runtime.h>
#include <math.h>

// Problem constants
#define Bq 8
#define Tt 128
#define Ee 384
#define Hh 768
#define Ll 9
#define GATE 1536   // 4*E

// ---------------------------------------------------------------------------
// Generic f32 GEMM: C[m,n] = sum_k A[m,k]*Bw[n,k] + b1[n] + b2[n] + bbn[m>>7][n]
// A row-major (M,K), Bw row-major (N,K), C row-major (M,N). grid.z batches via
// strides. BM=BN=128, BK=16, 256 threads, 8x8 microtile.
// ---------------------------------------------------------------------------
#define BM 128
#define BN 128
#define BKk 16

__global__ __launch_bounds__(256) void k_gemm(
    const float* __restrict__ A, const float* __restrict__ Bw, float* __restrict__ C,
    int M, int N, int K,
    long sAz, long sBz, long sCz,
    const float* __restrict__ b1, const float* __restrict__ b2, long sbz,
    const float* __restrict__ bbn)
{
    int z = blockIdx.z;
    A += (long)z * sAz;
    Bw += (long)z * sBz;
    C += (long)z * sCz;
    const float* bb1 = b1 ? b1 + (long)z * sbz : nullptr;
    const float* bb2 = b2 ? b2 + (long)z * sbz : nullptr;

    int n0 = blockIdx.x * BN;
    int m0 = blockIdx.y * BM;
    int tid = threadIdx.x;

    __shared__ float As[BKk][BM];
    __shared__ float Bs[BKk][BN];

    int lr = tid >> 2;          // 0..63
    int lc = (tid & 3) * 4;     // 0,4,8,12
    int tx = tid & 15;
    int ty = tid >> 4;

    float acc[8][8];
#pragma unroll
    for (int i = 0; i < 8; ++i)
#pragma unroll
        for (int j = 0; j < 8; ++j) acc[i][j] = 0.f;

    for (int k0 = 0; k0 < K; k0 += BKk) {
        float4 a0 = *(const float4*)&A[(long)(m0 + lr) * K + k0 + lc];
        float4 a1 = *(const float4*)&A[(long)(m0 + lr + 64) * K + k0 + lc];
        float4 w0 = *(const float4*)&Bw[(long)(n0 + lr) * K + k0 + lc];
        float4 w1 = *(const float4*)&Bw[(long)(n0 + lr + 64) * K + k0 + lc];
        __syncthreads();
        As[lc + 0][lr] = a0.x; As[lc + 1][lr] = a0.y; As[lc + 2][lr] = a0.z; As[lc + 3][lr] = a0.w;
        As[lc + 0][lr + 64] = a1.x; As[lc + 1][lr + 64] = a1.y; As[lc + 2][lr + 64] = a1.z; As[lc + 3][lr + 64] = a1.w;
        Bs[lc + 0][lr] = w0.x; Bs[lc + 1][lr] = w0.y; Bs[lc + 2][lr] = w0.z; Bs[lc + 3][lr] = w0.w;
        Bs[lc + 0][lr + 64] = w1.x; Bs[lc + 1][lr + 64] = w1.y; Bs[lc + 2][lr + 64] = w1.z; Bs[lc + 3][lr + 64] = w1.w;
        __syncthreads();
#pragma unroll
        for (int kk = 0; kk < BKk; ++kk) {
            float av[8], bv[8];
            *(float4*)&av[0] = *(float4*)&As[kk][ty * 8];
            *(float4*)&av[4] = *(float4*)&As[kk][ty * 8 + 4];
            *(float4*)&bv[0] = *(float4*)&Bs[kk][tx * 8];
            *(float4*)&bv[4] = *(float4*)&Bs[kk][tx * 8 + 4];
#pragma unroll
            for (int i = 0; i < 8; ++i)
#pragma unroll
                for (int j = 0; j < 8; ++j)
                    acc[i][j] = fmaf(av[i], bv[j], acc[i][j]);
        }
    }

#pragma unroll
    for (int i = 0; i < 8; ++i) {
        long m = m0 + ty * 8 + i;
#pragma unroll
        for (int j = 0; j < 8; ++j) {
            int n = n0 + tx * 8 + j;
            float val = acc[i][j];
            if (bb1) val += bb1[n];
            if (bb2) val += bb2[n];
            if (bbn) val += bbn[(m >> 7) * (long)N + n];
            C[m * N + n] = val;
        }
    }
}

// ---------------------------------------------------------------------------
// Flag-array grid barrier: 16 blocks per group, each block owns a 128B-spaced
// flag slot. Arrival = release-fence + relaxed store of (it+1). Wait = wave 0
// polls all 16 slots with one 16-lane load per sweep; one acquire fence after.
// ---------------------------------------------------------------------------
__device__ __forceinline__ void gbar2(unsigned* flags, int s, unsigned it1)
{
    __syncthreads();   // all waves' stores drained to L2 (vmcnt(0) before s_barrier)
    if (threadIdx.x < 64) {
        int lane = threadIdx.x & 63;
        if (lane == 0) {
            __builtin_amdgcn_fence(__ATOMIC_RELEASE, "agent");   // wbl2: flush dirty L2
            __hip_atomic_store(flags + s * 32, it1, __ATOMIC_RELAXED, __HIP_MEMORY_SCOPE_AGENT);
        }
        const unsigned* f = flags + (lane & 15) * 32;
        for (;;) {
            unsigned v = __hip_atomic_load(f, __ATOMIC_RELAXED, __HIP_MEMORY_SCOPE_AGENT);
            if (__all(v >= it1)) break;
            __builtin_amdgcn_s_sleep(2);
        }
        __builtin_amdgcn_fence(__ATOMIC_ACQUIRE, "agent");       // inv: drop stale lines
    }
    __syncthreads();
}

// ---------------------------------------------------------------------------
// LSTM recurrence for one layer (both directions), 32 blocks, normal launch.
// d = bid>>4, slice s = bid&15. Per-direction flag-array barrier (16 blocks).
// Each block owns 96 gate rows (24 h rows x 4 gates) of W_hh in registers.
// h exchanged via Yout global. c in registers. G prefetched one step ahead.
// G: [2][B*T][1536] precomputed input projections (+biases).
// Yout: [B][T][768] (fwd cols 0:384, bwd cols 384:768) = layer output.
// ---------------------------------------------------------------------------
__global__ __launch_bounds__(256, 1) void k_lstm(
    const float* __restrict__ G, const float* __restrict__ Whh, float* Yout,
    unsigned* barbase)
{
    int bid = blockIdx.x;
    int d = bid >> 4;
    int s = bid & 15;
    int tid = threadIdx.x;
    int kq = tid >> 5;          // 0..7  (k-range of 48)
    int rg = tid & 31;          // 0..31 (3 rows each)
    int kq48 = kq * 48;
    unsigned* flags = barbase + d * 512;   // 16 slots x 32 u32

    __shared__ float hl[8 * 384];       // h_prev for all batches of this dir
    __shared__ float part[8 * 776];     // partials: [kq][b(stride 97)][row 0..95]

    // Load W slice into registers
    float W_[3][48];
    const float* Wd = Whh + (long)d * GATE * Ee;
#pragma unroll
    for (int r = 0; r < 3; ++r) {
        int rl = rg * 3 + r;
        int g = rl / 24, rr = rl % 24;
        const float* src = Wd + (long)(g * Ee + s * 24 + rr) * Ee + kq48;
#pragma unroll
        for (int k4 = 0; k4 < 12; ++k4) {
            float4 w = *(const float4*)&src[k4 * 4];
            W_[r][k4 * 4 + 0] = w.x;
            W_[r][k4 * 4 + 1] = w.y;
            W_[r][k4 * 4 + 2] = w.z;
            W_[r][k4 * 4 + 3] = w.w;
        }
    }

    float cst = 0.f;                  // cell state for update thread
    int ub = tid / 24, ur = tid % 24; // update thread -> (batch, h-row)
    bool upd = tid < 192;

    // G prefetch (one timestep ahead)
    float gpre[4];
    const float* gbase = G + ((long)d * 1024 + ub * Tt) * GATE + s * 24 + ur;
    {
        int tt0 = d ? 127 : 0;
        if (upd) {
#pragma unroll
            for (int g = 0; g < 4; ++g) gpre[g] = gbase[(long)tt0 * GATE + g * Ee];
        }
    }

    float4* hl4 = (float4*)hl;

    for (int it = 0; it < 128; ++it) {
        int tt = d ? (127 - it) : it;
        int tp = d ? (tt + 1) : (tt - 1);

        // stage h_{prev} for all 8 batches (float4: 3 loads/thread)
        if (it == 0) {
            float4 z4 = make_float4(0.f, 0.f, 0.f, 0.f);
#pragma unroll
            for (int ii = 0; ii < 3; ++ii) hl4[tid + 256 * ii] = z4;
        } else {
#pragma unroll
            for (int ii = 0; ii < 3; ++ii) {
                int i4 = tid + 256 * ii;       // 0..767
                int b = i4 / 96, k4 = i4 - b * 96;
                hl4[i4] = *(const float4*)&Yout[((long)(b * Tt + tp)) * Hh + d * Ee + k4 * 4];
            }
        }
        __syncthreads();

        float acc[8][3];
#pragma unroll
        for (int b = 0; b < 8; ++b)
#pragma unroll
            for (int r = 0; r < 3; ++r) acc[b][r] = 0.f;

#pragma unroll
        for (int k4 = 0; k4 < 12; ++k4) {
#pragma unroll
            for (int b = 0; b < 8; ++b) {
                float4 hv = *(const float4*)&hl[b * 384 + kq48 + k4 * 4];
#pragma unroll
                for (int r = 0; r < 3; ++r) {
                    acc[b][r] = fmaf(W_[r][k4 * 4 + 0], hv.x, acc[b][r]);
                    acc[b][r] = fmaf(W_[r][k4 * 4 + 1], hv.y, acc[b][r]);
                    acc[b][r] = fmaf(W_[r][k4 * 4 + 2], hv.z, acc[b][r]);
                    acc[b][r] = fmaf(W_[r][k4 * 4 + 3], hv.w, acc[b][r]);
                }
            }
        }

        // write partials
#pragma unroll
        for (int b = 0; b < 8; ++b)
#pragma unroll
            for (int r = 0; r < 3; ++r)
                part[kq * 776 + b * 97 + rg * 3 + r] = acc[b][r];
        __syncthreads();

        if (upd) {
            float gt[4];
#pragma unroll
            for (int g = 0; g < 4; ++g) {
                int rl = g * 24 + ur;
                float sum = gpre[g];
#pragma unroll
                for (int q = 0; q < 8; ++q) sum += part[q * 776 + ub * 97 + rl];
                gt[g] = sum;
            }
            float ig = 1.f / (1.f + expf(-gt[0]));
            float fg = 1.f / (1.f + expf(-gt[1]));
            float gg = tanhf(gt[2]);
            float og = 1.f / (1.f + expf(-gt[3]));
            cst = fg * cst + ig * gg;
            float h = og * tanhf(cst);
            Yout[((long)(ub * Tt + tt)) * Hh + d * Ee + s * 24 + ur] = h;
        }
        if (it != 127) {
            // prefetch next step's G; latency hides under the barrier spin
            if (upd) {
                int ttn = d ? (tt - 1) : (tt + 1);
#pragma unroll
                for (int g = 0; g < 4; ++g) gpre[g] = gbase[(long)ttn * GATE + g * Ee];
            }
            gbar2(flags, s, (unsigned)(it + 1));
        }
    }
}

// ---------------------------------------------------------------------------
// p_term[b][n] = sum_k hs[b, qid[b], k] * W_p[n,k]
// grid (24, 8): blockIdx.y = b, blockIdx.x = 32-row chunk. 4 waves x 8 rows.
// ---------------------------------------------------------------------------
__global__ __launch_bounds__(256) void k_pterm(
    const float* __restrict__ hs, const int* __restrict__ qids,
    const float* __restrict__ Wp, float* __restrict__ pterm)
{
    int b = blockIdx.y;
    int chunk = blockIdx.x;
    int tid = threadIdx.x;
    int qid = qids[b];
    __shared__ float hp[Hh];
    for (int i = tid; i < Hh; i += 256) hp[i] = hs[((long)(b * Tt + qid)) * Hh + i];
    __syncthreads();
    int w = tid >> 6, lane = tid & 63;
#pragma unroll
    for (int r = 0; r < 8; ++r) {
        int n = chunk * 32 + w * 8 + r;
        const float* wrow = &Wp[(long)n * Hh];
        float p = 0.f;
#pragma unroll
        for (int k0 = 0; k0 < 3; ++k0) {
            int k = lane * 4 + k0 * 256;
            float4 wv = *(const float4*)&wrow[k];
            float4 hv = *(const float4*)&hp[k];
            p += wv.x * hv.x + wv.y * hv.y + wv.z * hv.z + wv.w * hv.w;
        }
#pragma unroll
        for (int o = 32; o; o >>= 1) p += __shfl_down(p, o);
        if (lane == 0) pterm[b * Hh + n] = p;
    }
}

// ---------------------------------------------------------------------------
// Fused attention per (b,t): scores -> softmax -> c -> logits. Stores a_mat
// (for pooling) and logits (for viterbi).
// ---------------------------------------------------------------------------
__global__ __launch_bounds__(256) void k_attn(
    const float* __restrict__ hs, const float* __restrict__ A1, const float* __restrict__ A2,
    const float* __restrict__ v, const float* __restrict__ Wclf,
    float* __restrict__ a_mat, float* __restrict__ logits)
{
    int b = blockIdx.x >> 7, t = blockIdx.x & 127;
    int tid = threadIdx.x;
    long bt = (long)(b * Tt + t);

    __shared__ float a2r[Hh], vr[Hh], hsr[Hh], crow[Hh];
    __shared__ float sc[128], tmp[256], red2[2];

    for (int i = tid; i < Hh; i += 256) {
        a2r[i] = A2[bt * Hh + i];
        vr[i] = v[i];
        hsr[i] = hs[bt * Hh + i];
    }
    __syncthreads();

    // scores: 2 threads per s (each 384 of 768)
    {
        int sid = tid >> 1, half = tid & 1;
        float p = 0.f;
        const float* A1r = &A1[((long)(b * Tt + sid)) * Hh + half * 384];
        const float* a2h = &a2r[half * 384];
        const float* vh = &vr[half * 384];
        for (int k = 0; k < 384; k += 4) {
            float4 z = *(const float4*)&A1r[k];
            p += vh[k + 0] * tanhf(z.x + a2h[k + 0]);
            p += vh[k + 1] * tanhf(z.y + a2h[k + 1]);
            p += vh[k + 2] * tanhf(z.z + a2h[k + 2]);
            p += vh[k + 3] * tanhf(z.w + a2h[k + 3]);
        }
        tmp[tid] = p;
    }
    __syncthreads();
    if (tid < 128) sc[tid] = tmp[2 * tid] + tmp[2 * tid + 1];
    __syncthreads();

    // softmax over s
    if (tid < 64) {
        float m = fmaxf(sc[tid], sc[tid + 64]);
#pragma unroll
        for (int o = 32; o; o >>= 1) m = fmaxf(m, __shfl_down(m, o));
        if (tid == 0) red2[0] = m;
    }
    __syncthreads();
    float mx = red2[0];
    if (tid < 128) sc[tid] = expf(sc[tid] - mx);
    __syncthreads();
    if (tid < 64) {
        float sm = sc[tid] + sc[tid + 64];
#pragma unroll
        for (int o = 32; o; o >>= 1) sm += __shfl_down(sm, o);
        if (tid == 0) red2[1] = sm;
    }
    __syncthreads();
    float inv = 1.f / red2[1];
    if (tid < 128) {
        sc[tid] *= inv;
        a_mat[bt * 128 + tid] = sc[tid];
    }
    __syncthreads();

    // c[b,t,:] = sum_s a_s * hs[b,s,:]
    float c0 = 0.f, c1 = 0.f, c2 = 0.f;
    for (int s2 = 0; s2 < 128; ++s2) {
        float as = sc[s2];
        const float* hrow = &hs[((long)(b * Tt + s2)) * Hh];
        c0 = fmaf(as, hrow[tid], c0);
        c1 = fmaf(as, hrow[tid + 256], c1);
        c2 = fmaf(as, hrow[tid + 512], c2);
    }
    crow[tid] = c0; crow[tid + 256] = c1; crow[tid + 512] = c2;
    __syncthreads();

    // logits[b,t,l] = [hs | c] . Wclf[l]
    for (int l = 0; l < Ll; ++l) {
        float p = 0.f;
        for (int h = tid; h < 2 * Hh; h += 256) {
            float u = (h < Hh) ? hsr[h] : crow[h - Hh];
            p = fmaf(u, Wclf[l * 2 * Hh + h], p);
        }
#pragma unroll
        for (int o = 32; o; o >>= 1) p += __shfl_down(p, o);
        if ((tid & 63) == 0) tmp[tid >> 6] = p;
        __syncthreads();
        if (tid == 0) logits[bt * Ll + l] = tmp[0] + tmp[1] + tmp[2] + tmp[3];
        __syncthreads();
    }
}

// ---------------------------------------------------------------------------
// a_t[b][s] = (sum_t a[b,t,s]) / (sum_s sum_t a[b,t,s])
// ---------------------------------------------------------------------------
__global__ void k_norm(const float* __restrict__ a_mat, float* __restrict__ a_t)
{
    int b = blockIdx.x;
    int s = threadIdx.x; // 128
    float sum = 0.f;
    for (int t = 0; t < Tt; ++t) sum += a_mat[((long)(b * Tt + t)) * 128 + s];
    __shared__ float pool[128];
    __shared__ float tot;
    pool[s] = sum;
    __syncthreads();
    if (s < 64) {
        float v2 = pool[s] + pool[s + 64];
#pragma unroll
        for (int o = 32; o; o >>= 1) v2 += __shfl_down(v2, o);
        if (s == 0) tot = v2;
    }
    __syncthreads();
    float tv = tot;
    a_t[b * 128 + s] = (tv != 0.f) ? pool[s] / tv : 0.f;
}

// ---------------------------------------------------------------------------
// Viterbi (L=9). One block. Strict-> argmax to match jnp.argmax first-max.
// ---------------------------------------------------------------------------
__global__ void k_viterbi(const float* __restrict__ logits, const float* __restrict__ trans,
                          const float* __restrict__ start, const float* __restrict__ endw,
                          float* __restrict__ out)
{
    __shared__ float sc[2][72];
    __shared__ unsigned char ptrs[127][72];
    __shared__ unsigned char tags[8][128];
    int tid = threadIdx.x;
    int b = tid / 9, j = tid % 9;
    bool act = tid < 72;
    if (act) sc[0][b * 9 + j] = start[j] + logits[(b * Tt + 0) * Ll + j];
    __syncthreads();
    for (int t = 1; t < Tt; ++t) {
        int cur = t & 1, prv = cur ^ 1;
        if (act) {
            float best = -1e30f; int bi = 0;
#pragma unroll
            for (int i = 0; i < 9; ++i) {
                float vv = sc[prv][b * 9 + i] + trans[i * 9 + j];
                if (vv > best) { best = vv; bi = i; }
            }
            sc[cur][b * 9 + j] = best + logits[(b * Tt + t) * Ll + j];
            ptrs[t - 1][b * 9 + j] = (unsigned char)bi;
        }
        __syncthreads();
    }
    if (act && j == 0) {
        float best = -1e30f; int bj = 0;
#pragma unroll
        for (int jj = 0; jj < 9; ++jj) {
            float vv = sc[1][b * 9 + jj] + endw[jj];
            if (vv > best) { best = vv; bj = jj; }
        }
        int tg = bj;
        tags[b][127] = (unsigned char)tg;
        for (int t = 127; t >= 1; --t) {
            tg = ptrs[t - 1][b * 9 + tg];
            tags[b][t - 1] = (unsigned char)tg;
        }
    }
    __syncthreads();
    for (int i = tid; i < Bq * Tt * Ll; i += blockDim.x) {
        int l = i % 9;
        int btx = i / 9;
        int tt2 = btx % Tt;
        int bb = btx / Tt;
        out[i] = (tags[bb][tt2] == l) ? 10.f : -1.f;
    }
}

// ---------------------------------------------------------------------------
extern "C" void kernel_launch(void* const* d_in, const int* in_sizes, int n_in,
                              void* d_out, int out_size, void* d_ws, size_t ws_size,
                              hipStream_t stream)
{
    const float* embeds   = (const float*)d_in[0];
    const int*   qids     = (const int*)d_in[1];
    const float* w_ih_l0  = (const float*)d_in[2];
    const float* w_ih_rest= (const float*)d_in[3];
    const float* w_hh     = (const float*)d_in[4];
    const float* b_ih     = (const float*)d_in[5];
    const float* b_hh     = (const float*)d_in[6];
    const float* W_H      = (const float*)d_in[7];
    const float* W_p      = (const float*)d_in[8];
    const float* W_h      = (const float*)d_in[9];
    const float* vvec     = (const float*)d_in[10];
    const float* W_clf    = (const float*)d_in[11];
    const float* trans    = (const float*)d_in[12];
    const float* cstart   = (const float*)d_in[13];
    const float* cend     = (const float*)d_in[14];

    float* out = (float*)d_out;
    float* vit_out = out;                          // 8*128*9   = 9216
    float* hs      = out + 9216;                   // 8*128*768 = 786432
    float* a_t     = out + 9216 + 786432;          // 8*128     = 1024

    // Workspace overlay:
    //  phase A (LSTM):   G [3145728] | Y0 [786432] | Y1 [786432] | bar flags
    //  phase B (attn):   A1,A2,pterm,a_mat,logits all inside G's region
    float* ws = (float*)d_ws;
    float* G      = ws;                  // 3145728 floats
    float* Y0     = ws + 3145728;        // 786432
    float* Y1     = Y0 + 786432;         // 786432
    unsigned* bar = (unsigned*)(ws + 3145728 + 2 * 786432);  // 3*1024 u32
    float* A1     = ws;                  // reuses G (dead after last lstm)
    float* A2     = A1 + 786432;
    float* pterm  = A2 + 786432;         // 6144
    float* a_mat  = pterm + 6144;        // 131072
    float* logits = a_mat + 131072;      // 9216  (ends well inside G region)

    dim3 blk(256);

    // Reset barrier flags every call (deterministic, capture-safe).
    hipMemsetAsync(bar, 0, 3 * 1024 * sizeof(unsigned), stream);

    // ---- Layer 0 ----
    k_gemm<<<dim3(GATE / BN, 1024 / BM, 2), blk, 0, stream>>>(
        embeds, w_ih_l0, G, 1024, GATE, Ee,
        0L, (long)GATE * Ee, (long)1024 * GATE,
        b_ih, b_hh, (long)GATE, nullptr);
    k_lstm<<<dim3(32), blk, 0, stream>>>(G, w_hh, Y0, bar);

    // ---- Layer 1 ----
    k_gemm<<<dim3(GATE / BN, 1024 / BM, 2), blk, 0, stream>>>(
        Y0, w_ih_rest, G, 1024, GATE, Hh,
        0L, (long)GATE * Hh, (long)1024 * GATE,
        b_ih + 2 * GATE, b_hh + 2 * GATE, (long)GATE, nullptr);
    k_lstm<<<dim3(32), blk, 0, stream>>>(G, w_hh + (long)2 * GATE * Ee, Y1, bar + 1024);

    // ---- Layer 2 ----
    k_gemm<<<dim3(GATE / BN, 1024 / BM, 2), blk, 0, stream>>>(
        Y1, w_ih_rest + (long)2 * GATE * Hh, G, 1024, GATE, Hh,
        0L, (long)GATE * Hh, (long)1024 * GATE,
        b_ih + 4 * GATE, b_hh + 4 * GATE, (long)GATE, nullptr);
    k_lstm<<<dim3(32), blk, 0, stream>>>(G, w_hh + (long)4 * GATE * Ee, hs, bar + 2048);

    // ---- Attention precompute ----
    k_pterm<<<dim3(24, 8), blk, 0, stream>>>(hs, qids, W_p, pterm);
    k_gemm<<<dim3(Hh / BN, 1024 / BM, 1), blk, 0, stream>>>(
        hs, W_H, A1, 1024, Hh, Hh, 0L, 0L, 0L, nullptr, nullptr, 0L, nullptr);
    k_gemm<<<dim3(Hh / BN, 1024 / BM, 1), blk, 0, stream>>>(
        hs, W_h, A2, 1024, Hh, Hh, 0L, 0L, 0L, nullptr, nullptr, 0L, pterm);

    // ---- Fused attention + logits ----
    k_attn<<<dim3(1024), blk, 0, stream>>>(hs, A1, A2, vvec, W_clf, a_mat, logits);

    // ---- Pooled attention norm -> a_t ----
    k_norm<<<dim3(8), dim3(128), 0, stream>>>(a_mat, a_t);

    // ---- Viterbi -> vit_logits ----
    k_viterbi<<<dim3(1), dim3(128), 0, stream>>>(logits, trans, cstart, cend, vit_out);
}

// Round 5
// 2584.814 us; speedup vs baseline: 1.4564x; 1.0293x over previous
//
#include <hip/hip_runtime.h>
#include <math.h>

// Problem constants
#define Bq 8
#define Tt 128
#define Ee 384
#define Hh 768
#define Ll 9
#define GATE 1536   // 4*E

__device__ __forceinline__ float fast_sigmoid(float x) {
    return 1.f / (1.f + __expf(-x));
}
__device__ __forceinline__ float fast_tanh(float x) {
    // tanh(x) = 1 - 2/(e^{2x}+1); __expf saturates for large |x| -> ±1 exactly
    return 1.f - 2.f / (__expf(2.f * x) + 1.f);
}

// ---------------------------------------------------------------------------
// Generic f32 GEMM: C[m,n] = sum_k A[m,k]*Bw[n,k] + b1[n] + b2[n] + bbn[m>>7][n]
// ---------------------------------------------------------------------------
#define BM 128
#define BN 128
#define BKk 16

__global__ __launch_bounds__(256) void k_gemm(
    const float* __restrict__ A, const float* __restrict__ Bw, float* __restrict__ C,
    int M, int N, int K,
    long sAz, long sBz, long sCz,
    const float* __restrict__ b1, const float* __restrict__ b2, long sbz,
    const float* __restrict__ bbn)
{
    int z = blockIdx.z;
    A += (long)z * sAz;
    Bw += (long)z * sBz;
    C += (long)z * sCz;
    const float* bb1 = b1 ? b1 + (long)z * sbz : nullptr;
    const float* bb2 = b2 ? b2 + (long)z * sbz : nullptr;

    int n0 = blockIdx.x * BN;
    int m0 = blockIdx.y * BM;
    int tid = threadIdx.x;

    __shared__ float As[BKk][BM];
    __shared__ float Bs[BKk][BN];

    int lr = tid >> 2;          // 0..63
    int lc = (tid & 3) * 4;     // 0,4,8,12
    int tx = tid & 15;
    int ty = tid >> 4;

    float acc[8][8];
#pragma unroll
    for (int i = 0; i < 8; ++i)
#pragma unroll
        for (int j = 0; j < 8; ++j) acc[i][j] = 0.f;

    for (int k0 = 0; k0 < K; k0 += BKk) {
        float4 a0 = *(const float4*)&A[(long)(m0 + lr) * K + k0 + lc];
        float4 a1 = *(const float4*)&A[(long)(m0 + lr + 64) * K + k0 + lc];
        float4 w0 = *(const float4*)&Bw[(long)(n0 + lr) * K + k0 + lc];
        float4 w1 = *(const float4*)&Bw[(long)(n0 + lr + 64) * K + k0 + lc];
        __syncthreads();
        As[lc + 0][lr] = a0.x; As[lc + 1][lr] = a0.y; As[lc + 2][lr] = a0.z; As[lc + 3][lr] = a0.w;
        As[lc + 0][lr + 64] = a1.x; As[lc + 1][lr + 64] = a1.y; As[lc + 2][lr + 64] = a1.z; As[lc + 3][lr + 64] = a1.w;
        Bs[lc + 0][lr] = w0.x; Bs[lc + 1][lr] = w0.y; Bs[lc + 2][lr] = w0.z; Bs[lc + 3][lr] = w0.w;
        Bs[lc + 0][lr + 64] = w1.x; Bs[lc + 1][lr + 64] = w1.y; Bs[lc + 2][lr + 64] = w1.z; Bs[lc + 3][lr + 64] = w1.w;
        __syncthreads();
#pragma unroll
        for (int kk = 0; kk < BKk; ++kk) {
            float av[8], bv[8];
            *(float4*)&av[0] = *(float4*)&As[kk][ty * 8];
            *(float4*)&av[4] = *(float4*)&As[kk][ty * 8 + 4];
            *(float4*)&bv[0] = *(float4*)&Bs[kk][tx * 8];
            *(float4*)&bv[4] = *(float4*)&Bs[kk][tx * 8 + 4];
#pragma unroll
            for (int i = 0; i < 8; ++i)
#pragma unroll
                for (int j = 0; j < 8; ++j)
                    acc[i][j] = fmaf(av[i], bv[j], acc[i][j]);
        }
    }

#pragma unroll
    for (int i = 0; i < 8; ++i) {
        long m = m0 + ty * 8 + i;
#pragma unroll
        for (int j = 0; j < 8; ++j) {
            int n = n0 + tx * 8 + j;
            float val = acc[i][j];
            if (bb1) val += bb1[n];
            if (bb2) val += bb2[n];
            if (bbn) val += bbn[(m >> 7) * (long)N + n];
            C[m * N + n] = val;
        }
    }
}

// ---------------------------------------------------------------------------
// LSTM recurrence, fence-free cross-block exchange.
// 32 blocks: d = bid>>4, slice s = bid&15. h values and flags are agent-scope
// relaxed atomics: write-through to the device coherence point and loads that
// bypass stale L1/L2 — no buffer_wbl2 / buffer_inv on the step critical path.
// Ordering: h stores -> s_waitcnt vmcnt(0) -> syncthreads -> flag store.
// Reader: poll flag -> atomic h loads.
// ---------------------------------------------------------------------------
__global__ __launch_bounds__(256, 1) void k_lstm(
    const float* __restrict__ G, const float* __restrict__ Whh, float* Yout,
    unsigned* barbase)
{
    int bid = blockIdx.x;
    int d = bid >> 4;
    int s = bid & 15;
    int tid = threadIdx.x;
    int kq = tid >> 5;          // 0..7  (k-range of 48)
    int rg = tid & 31;          // 0..31 (3 rows each)
    int kq48 = kq * 48;
    unsigned* flags = barbase + d * 512;   // 16 slots x 32 u32 (128B spacing)

    __shared__ float hl[8 * 384];       // h_prev for all batches of this dir
    __shared__ float part[8 * 776];     // partials: [kq][b(stride 97)][row 0..95]

    // Load W slice into registers
    float W_[3][48];
    const float* Wd = Whh + (long)d * GATE * Ee;
#pragma unroll
    for (int r = 0; r < 3; ++r) {
        int rl = rg * 3 + r;
        int g = rl / 24, rr = rl % 24;
        const float* src = Wd + (long)(g * Ee + s * 24 + rr) * Ee + kq48;
#pragma unroll
        for (int k4 = 0; k4 < 12; ++k4) {
            float4 w = *(const float4*)&src[k4 * 4];
            W_[r][k4 * 4 + 0] = w.x;
            W_[r][k4 * 4 + 1] = w.y;
            W_[r][k4 * 4 + 2] = w.z;
            W_[r][k4 * 4 + 3] = w.w;
        }
    }

    float cst = 0.f;                  // cell state for update thread
    int ub = tid / 24, ur = tid % 24; // update thread -> (batch, h-row)
    bool upd = tid < 192;

    // G prefetch (one timestep ahead)
    float gpre[4];
    const float* gbase = G + ((long)d * 1024 + ub * Tt) * GATE + s * 24 + ur;
    {
        int tt0 = d ? 127 : 0;
        if (upd) {
#pragma unroll
            for (int g = 0; g < 4; ++g) gpre[g] = gbase[(long)tt0 * GATE + g * Ee];
        }
    }

    float4* hl4 = (float4*)hl;

    for (int it = 0; it < 128; ++it) {
        int tt = d ? (127 - it) : it;
        int tp = d ? (tt + 1) : (tt - 1);

        // stage h_{prev} for all 8 batches (atomic 8B loads bypass stale caches)
        if (it == 0) {
            float4 z4 = make_float4(0.f, 0.f, 0.f, 0.f);
#pragma unroll
            for (int ii = 0; ii < 3; ++ii) hl4[tid + 256 * ii] = z4;
        } else {
#pragma unroll
            for (int ii = 0; ii < 3; ++ii) {
                int i4 = tid + 256 * ii;       // 0..767
                int b = i4 / 96, k4 = i4 - b * 96;
                const unsigned long long* src = (const unsigned long long*)
                    &Yout[((long)(b * Tt + tp)) * Hh + d * Ee + k4 * 4];
                unsigned long long lo = __hip_atomic_load(src,     __ATOMIC_RELAXED, __HIP_MEMORY_SCOPE_AGENT);
                unsigned long long hi = __hip_atomic_load(src + 1, __ATOMIC_RELAXED, __HIP_MEMORY_SCOPE_AGENT);
                float2 flo = __builtin_bit_cast(float2, lo);
                float2 fhi = __builtin_bit_cast(float2, hi);
                hl4[i4] = make_float4(flo.x, flo.y, fhi.x, fhi.y);
            }
        }
        __syncthreads();

        float acc[8][3];
#pragma unroll
        for (int b = 0; b < 8; ++b)
#pragma unroll
            for (int r = 0; r < 3; ++r) acc[b][r] = 0.f;

#pragma unroll
        for (int k4 = 0; k4 < 12; ++k4) {
#pragma unroll
            for (int b = 0; b < 8; ++b) {
                float4 hv = *(const float4*)&hl[b * 384 + kq48 + k4 * 4];
#pragma unroll
                for (int r = 0; r < 3; ++r) {
                    acc[b][r] = fmaf(W_[r][k4 * 4 + 0], hv.x, acc[b][r]);
                    acc[b][r] = fmaf(W_[r][k4 * 4 + 1], hv.y, acc[b][r]);
                    acc[b][r] = fmaf(W_[r][k4 * 4 + 2], hv.z, acc[b][r]);
                    acc[b][r] = fmaf(W_[r][k4 * 4 + 3], hv.w, acc[b][r]);
                }
            }
        }

        // write partials
#pragma unroll
        for (int b = 0; b < 8; ++b)
#pragma unroll
            for (int r = 0; r < 3; ++r)
                part[kq * 776 + b * 97 + rg * 3 + r] = acc[b][r];
        __syncthreads();

        if (upd) {
            float gt[4];
#pragma unroll
            for (int g = 0; g < 4; ++g) {
                int rl = g * 24 + ur;
                float sum = gpre[g];
#pragma unroll
                for (int q = 0; q < 8; ++q) sum += part[q * 776 + ub * 97 + rl];
                gt[g] = sum;
            }
            float ig = fast_sigmoid(gt[0]);
            float fg = fast_sigmoid(gt[1]);
            float gg = fast_tanh(gt[2]);
            float og = fast_sigmoid(gt[3]);
            cst = fg * cst + ig * gg;
            float h = og * fast_tanh(cst);
            // write-through store to the device coherence point
            __hip_atomic_store(&Yout[((long)(ub * Tt + tt)) * Hh + d * Ee + s * 24 + ur],
                               h, __ATOMIC_RELAXED, __HIP_MEMORY_SCOPE_AGENT);
        }

        if (it != 127) {
            // prefetch next step's G; latency hides under the barrier
            if (upd) {
                int ttn = d ? (tt - 1) : (tt + 1);
#pragma unroll
                for (int g = 0; g < 4; ++g) gpre[g] = gbase[(long)ttn * GATE + g * Ee];
            }
            // ---- fence-free barrier ----
            asm volatile("s_waitcnt vmcnt(0)" ::: "memory");  // h at coherence point
            __syncthreads();                                   // all waves' stores done
            unsigned it1 = (unsigned)(it + 1);
            if (tid == 0)
                __hip_atomic_store(flags + s * 32, it1, __ATOMIC_RELAXED, __HIP_MEMORY_SCOPE_AGENT);
            if (tid < 64) {
                const unsigned* f = flags + (tid & 15) * 32;
                unsigned v;
                do {
                    v = __hip_atomic_load(f, __ATOMIC_RELAXED, __HIP_MEMORY_SCOPE_AGENT);
                } while (!__all(v >= it1));
            }
            __syncthreads();
            asm volatile("" ::: "memory");
        }
    }
}

// ---------------------------------------------------------------------------
// p_term[b][n] = sum_k hs[b, qid[b], k] * W_p[n,k]
// grid (24, 8): blockIdx.y = b, blockIdx.x = 32-row chunk. 4 waves x 8 rows.
// ---------------------------------------------------------------------------
__global__ __launch_bounds__(256) void k_pterm(
    const float* __restrict__ hs, const int* __restrict__ qids,
    const float* __restrict__ Wp, float* __restrict__ pterm)
{
    int b = blockIdx.y;
    int chunk = blockIdx.x;
    int tid = threadIdx.x;
    int qid = qids[b];
    __shared__ float hp[Hh];
    for (int i = tid; i < Hh; i += 256) hp[i] = hs[((long)(b * Tt + qid)) * Hh + i];
    __syncthreads();
    int w = tid >> 6, lane = tid & 63;
#pragma unroll
    for (int r = 0; r < 8; ++r) {
        int n = chunk * 32 + w * 8 + r;
        const float* wrow = &Wp[(long)n * Hh];
        float p = 0.f;
#pragma unroll
        for (int k0 = 0; k0 < 3; ++k0) {
            int k = lane * 4 + k0 * 256;
            float4 wv = *(const float4*)&wrow[k];
            float4 hv = *(const float4*)&hp[k];
            p += wv.x * hv.x + wv.y * hv.y + wv.z * hv.z + wv.w * hv.w;
        }
#pragma unroll
        for (int o = 32; o; o >>= 1) p += __shfl_down(p, o);
        if (lane == 0) pterm[b * Hh + n] = p;
    }
}

// ---------------------------------------------------------------------------
// Fused attention per (b,t): scores -> softmax -> c -> logits.
// ---------------------------------------------------------------------------
__global__ __launch_bounds__(256) void k_attn(
    const float* __restrict__ hs, const float* __restrict__ A1, const float* __restrict__ A2,
    const float* __restrict__ v, const float* __restrict__ Wclf,
    float* __restrict__ a_mat, float* __restrict__ logits)
{
    int b = blockIdx.x >> 7, t = blockIdx.x & 127;
    int tid = threadIdx.x;
    long bt = (long)(b * Tt + t);

    __shared__ float a2r[Hh], vr[Hh], hsr[Hh], crow[Hh];
    __shared__ float sc[128], tmp[256], red2[2];

    for (int i = tid; i < Hh; i += 256) {
        a2r[i] = A2[bt * Hh + i];
        vr[i] = v[i];
        hsr[i] = hs[bt * Hh + i];
    }
    __syncthreads();

    // scores: 2 threads per s (each 384 of 768)
    {
        int sid = tid >> 1, half = tid & 1;
        float p = 0.f;
        const float* A1r = &A1[((long)(b * Tt + sid)) * Hh + half * 384];
        const float* a2h = &a2r[half * 384];
        const float* vh = &vr[half * 384];
        for (int k = 0; k < 384; k += 4) {
            float4 z = *(const float4*)&A1r[k];
            p += vh[k + 0] * fast_tanh(z.x + a2h[k + 0]);
            p += vh[k + 1] * fast_tanh(z.y + a2h[k + 1]);
            p += vh[k + 2] * fast_tanh(z.z + a2h[k + 2]);
            p += vh[k + 3] * fast_tanh(z.w + a2h[k + 3]);
        }
        tmp[tid] = p;
    }
    __syncthreads();
    if (tid < 128) sc[tid] = tmp[2 * tid] + tmp[2 * tid + 1];
    __syncthreads();

    // softmax over s
    if (tid < 64) {
        float m = fmaxf(sc[tid], sc[tid + 64]);
#pragma unroll
        for (int o = 32; o; o >>= 1) m = fmaxf(m, __shfl_down(m, o));
        if (tid == 0) red2[0] = m;
    }
    __syncthreads();
    float mx = red2[0];
    if (tid < 128) sc[tid] = __expf(sc[tid] - mx);
    __syncthreads();
    if (tid < 64) {
        float sm = sc[tid] + sc[tid + 64];
#pragma unroll
        for (int o = 32; o; o >>= 1) sm += __shfl_down(sm, o);
        if (tid == 0) red2[1] = sm;
    }
    __syncthreads();
    float inv = 1.f / red2[1];
    if (tid < 128) {
        sc[tid] *= inv;
        a_mat[bt * 128 + tid] = sc[tid];
    }
    __syncthreads();

    // c[b,t,:] = sum_s a_s * hs[b,s,:]
    float c0 = 0.f, c1 = 0.f, c2 = 0.f;
    for (int s2 = 0; s2 < 128; ++s2) {
        float as = sc[s2];
        const float* hrow = &hs[((long)(b * Tt + s2)) * Hh];
        c0 = fmaf(as, hrow[tid], c0);
        c1 = fmaf(as, hrow[tid + 256], c1);
        c2 = fmaf(as, hrow[tid + 512], c2);
    }
    crow[tid] = c0; crow[tid + 256] = c1; crow[tid + 512] = c2;
    __syncthreads();

    // logits[b,t,l] = [hs | c] . Wclf[l]
    for (int l = 0; l < Ll; ++l) {
        float p = 0.f;
        for (int h = tid; h < 2 * Hh; h += 256) {
            float u = (h < Hh) ? hsr[h] : crow[h - Hh];
            p = fmaf(u, Wclf[l * 2 * Hh + h], p);
        }
#pragma unroll
        for (int o = 32; o; o >>= 1) p += __shfl_down(p, o);
        if ((tid & 63) == 0) tmp[tid >> 6] = p;
        __syncthreads();
        if (tid == 0) logits[bt * Ll + l] = tmp[0] + tmp[1] + tmp[2] + tmp[3];
        __syncthreads();
    }
}

// ---------------------------------------------------------------------------
// a_t[b][s] = (sum_t a[b,t,s]) / (sum_s sum_t a[b,t,s])
// ---------------------------------------------------------------------------
__global__ void k_norm(const float* __restrict__ a_mat, float* __restrict__ a_t)
{
    int b = blockIdx.x;
    int s = threadIdx.x; // 128
    float sum = 0.f;
    for (int t = 0; t < Tt; ++t) sum += a_mat[((long)(b * Tt + t)) * 128 + s];
    __shared__ float pool[128];
    __shared__ float tot;
    pool[s] = sum;
    __syncthreads();
    if (s < 64) {
        float v2 = pool[s] + pool[s + 64];
#pragma unroll
        for (int o = 32; o; o >>= 1) v2 += __shfl_down(v2, o);
        if (s == 0) tot = v2;
    }
    __syncthreads();
    float tv = tot;
    a_t[b * 128 + s] = (tv != 0.f) ? pool[s] / tv : 0.f;
}

// ---------------------------------------------------------------------------
// Viterbi (L=9). One block. Strict-> argmax to match jnp.argmax first-max.
// ---------------------------------------------------------------------------
__global__ void k_viterbi(const float* __restrict__ logits, const float* __restrict__ trans,
                          const float* __restrict__ start, const float* __restrict__ endw,
                          float* __restrict__ out)
{
    __shared__ float sc[2][72];
    __shared__ unsigned char ptrs[127][72];
    __shared__ unsigned char tags[8][128];
    int tid = threadIdx.x;
    int b = tid / 9, j = tid % 9;
    bool act = tid < 72;
    if (act) sc[0][b * 9 + j] = start[j] + logits[(b * Tt + 0) * Ll + j];
    __syncthreads();
    for (int t = 1; t < Tt; ++t) {
        int cur = t & 1, prv = cur ^ 1;
        if (act) {
            float best = -1e30f; int bi = 0;
#pragma unroll
            for (int i = 0; i < 9; ++i) {
                float vv = sc[prv][b * 9 + i] + trans[i * 9 + j];
                if (vv > best) { best = vv; bi = i; }
            }
            sc[cur][b * 9 + j] = best + logits[(b * Tt + t) * Ll + j];
            ptrs[t - 1][b * 9 + j] = (unsigned char)bi;
        }
        __syncthreads();
    }
    if (act && j == 0) {
        float best = -1e30f; int bj = 0;
#pragma unroll
        for (int jj = 0; jj < 9; ++jj) {
            float vv = sc[1][b * 9 + jj] + endw[jj];
            if (vv > best) { best = vv; bj = jj; }
        }
        int tg = bj;
        tags[b][127] = (unsigned char)tg;
        for (int t = 127; t >= 1; --t) {
            tg = ptrs[t - 1][b * 9 + tg];
            tags[b][t - 1] = (unsigned char)tg;
        }
    }
    __syncthreads();
    for (int i = tid; i < Bq * Tt * Ll; i += blockDim.x) {
        int l = i % 9;
        int btx = i / 9;
        int tt2 = btx % Tt;
        int bb = btx / Tt;
        out[i] = (tags[bb][tt2] == l) ? 10.f : -1.f;
    }
}

// ---------------------------------------------------------------------------
extern "C" void kernel_launch(void* const* d_in, const int* in_sizes, int n_in,
                              void* d_out, int out_size, void* d_ws, size_t ws_size,
                              hipStream_t stream)
{
    const float* embeds   = (const float*)d_in[0];
    const int*   qids     = (const int*)d_in[1];
    const float* w_ih_l0  = (const float*)d_in[2];
    const float* w_ih_rest= (const float*)d_in[3];
    const float* w_hh     = (const float*)d_in[4];
    const float* b_ih     = (const float*)d_in[5];
    const float* b_hh     = (const float*)d_in[6];
    const float* W_H      = (const float*)d_in[7];
    const float* W_p      = (const float*)d_in[8];
    const float* W_h      = (const float*)d_in[9];
    const float* vvec     = (const float*)d_in[10];
    const float* W_clf    = (const float*)d_in[11];
    const float* trans    = (const float*)d_in[12];
    const float* cstart   = (const float*)d_in[13];
    const float* cend     = (const float*)d_in[14];

    float* out = (float*)d_out;
    float* vit_out = out;                          // 8*128*9   = 9216
    float* hs      = out + 9216;                   // 8*128*768 = 786432
    float* a_t     = out + 9216 + 786432;          // 8*128     = 1024

    // Workspace overlay:
    //  phase A (LSTM):   G [3145728] | Y0 [786432] | Y1 [786432] | bar flags
    //  phase B (attn):   A1,A2,pterm,a_mat,logits all inside G's region
    float* ws = (float*)d_ws;
    float* G      = ws;                  // 3145728 floats
    float* Y0     = ws + 3145728;        // 786432
    float* Y1     = Y0 + 786432;         // 786432
    unsigned* bar = (unsigned*)(ws + 3145728 + 2 * 786432);  // 3*1024 u32
    float* A1     = ws;                  // reuses G (dead after last lstm)
    float* A2     = A1 + 786432;
    float* pterm  = A2 + 786432;         // 6144
    float* a_mat  = pterm + 6144;        // 131072
    float* logits = a_mat + 131072;      // 9216  (ends well inside G region)

    dim3 blk(256);

    // Reset barrier flags every call (deterministic, capture-safe).
    (void)hipMemsetAsync(bar, 0, 3 * 1024 * sizeof(unsigned), stream);

    // ---- Layer 0 ----
    k_gemm<<<dim3(GATE / BN, 1024 / BM, 2), blk, 0, stream>>>(
        embeds, w_ih_l0, G, 1024, GATE, Ee,
        0L, (long)GATE * Ee, (long)1024 * GATE,
        b_ih, b_hh, (long)GATE, nullptr);
    k_lstm<<<dim3(32), blk, 0, stream>>>(G, w_hh, Y0, bar);

    // ---- Layer 1 ----
    k_gemm<<<dim3(GATE / BN, 1024 / BM, 2), blk, 0, stream>>>(
        Y0, w_ih_rest, G, 1024, GATE, Hh,
        0L, (long)GATE * Hh, (long)1024 * GATE,
        b_ih + 2 * GATE, b_hh + 2 * GATE, (long)GATE, nullptr);
    k_lstm<<<dim3(32), blk, 0, stream>>>(G, w_hh + (long)2 * GATE * Ee, Y1, bar + 1024);

    // ---- Layer 2 ----
    k_gemm<<<dim3(GATE / BN, 1024 / BM, 2), blk, 0, stream>>>(
        Y1, w_ih_rest + (long)2 * GATE * Hh, G, 1024, GATE, Hh,
        0L, (long)GATE * Hh, (long)1024 * GATE,
        b_ih + 4 * GATE, b_hh + 4 * GATE, (long)GATE, nullptr);
    k_lstm<<<dim3(32), blk, 0, stream>>>(G, w_hh + (long)4 * GATE * Ee, hs, bar + 2048);

    // ---- Attention precompute ----
    k_pterm<<<dim3(24, 8), blk, 0, stream>>>(hs, qids, W_p, pterm);
    k_gemm<<<dim3(Hh / BN, 1024 / BM, 1), blk, 0, stream>>>(
        hs, W_H, A1, 1024, Hh, Hh, 0L, 0L, 0L, nullptr, nullptr, 0L, nullptr);
    k_gemm<<<dim3(Hh / BN, 1024 / BM, 1), blk, 0, stream>>>(
        hs, W_h, A2, 1024, Hh, Hh, 0L, 0L, 0L, nullptr, nullptr, 0L, pterm);

    // ---- Fused attention + logits ----
    k_attn<<<dim3(1024), blk, 0, stream>>>(hs, A1, A2, vvec, W_clf, a_mat, logits);

    // ---- Pooled attention norm -> a_t ----
    k_norm<<<dim3(8), dim3(128), 0, stream>>>(a_mat, a_t);

    // ---- Viterbi -> vit_logits ----
    k_viterbi<<<dim3(1), dim3(128), 0, stream>>>(logits, trans, cstart, cend, vit_out);
}

// Round 6
// 2558.826 us; speedup vs baseline: 1.4712x; 1.0102x over previous
//
#include <hip/hip_runtime.h>
#include <math.h>

// Problem constants
#define Bq 8
#define Tt 128
#define Ee 384
#define Hh 768
#define Ll 9
#define GATE 1536   // 4*E

__device__ __forceinline__ float fast_sigmoid(float x) {
    return 1.f / (1.f + __expf(-x));
}
__device__ __forceinline__ float fast_tanh(float x) {
    // tanh(x) = 1 - 2/(e^{2x}+1); __expf saturates for large |x| -> ±1 exactly
    return 1.f - 2.f / (__expf(2.f * x) + 1.f);
}

// ---------------------------------------------------------------------------
// Generic f32 GEMM: C[m,n] = sum_k A[m,k]*Bw[n,k] + b1[n] + b2[n] + bbn[m>>7][n]
// ---------------------------------------------------------------------------
#define BM 128
#define BN 128
#define BKk 16

__global__ __launch_bounds__(256) void k_gemm(
    const float* __restrict__ A, const float* __restrict__ Bw, float* __restrict__ C,
    int M, int N, int K,
    long sAz, long sBz, long sCz,
    const float* __restrict__ b1, const float* __restrict__ b2, long sbz,
    const float* __restrict__ bbn)
{
    int z = blockIdx.z;
    A += (long)z * sAz;
    Bw += (long)z * sBz;
    C += (long)z * sCz;
    const float* bb1 = b1 ? b1 + (long)z * sbz : nullptr;
    const float* bb2 = b2 ? b2 + (long)z * sbz : nullptr;

    int n0 = blockIdx.x * BN;
    int m0 = blockIdx.y * BM;
    int tid = threadIdx.x;

    __shared__ float As[BKk][BM];
    __shared__ float Bs[BKk][BN];

    int lr = tid >> 2;          // 0..63
    int lc = (tid & 3) * 4;     // 0,4,8,12
    int tx = tid & 15;
    int ty = tid >> 4;

    float acc[8][8];
#pragma unroll
    for (int i = 0; i < 8; ++i)
#pragma unroll
        for (int j = 0; j < 8; ++j) acc[i][j] = 0.f;

    for (int k0 = 0; k0 < K; k0 += BKk) {
        float4 a0 = *(const float4*)&A[(long)(m0 + lr) * K + k0 + lc];
        float4 a1 = *(const float4*)&A[(long)(m0 + lr + 64) * K + k0 + lc];
        float4 w0 = *(const float4*)&Bw[(long)(n0 + lr) * K + k0 + lc];
        float4 w1 = *(const float4*)&Bw[(long)(n0 + lr + 64) * K + k0 + lc];
        __syncthreads();
        As[lc + 0][lr] = a0.x; As[lc + 1][lr] = a0.y; As[lc + 2][lr] = a0.z; As[lc + 3][lr] = a0.w;
        As[lc + 0][lr + 64] = a1.x; As[lc + 1][lr + 64] = a1.y; As[lc + 2][lr + 64] = a1.z; As[lc + 3][lr + 64] = a1.w;
        Bs[lc + 0][lr] = w0.x; Bs[lc + 1][lr] = w0.y; Bs[lc + 2][lr] = w0.z; Bs[lc + 3][lr] = w0.w;
        Bs[lc + 0][lr + 64] = w1.x; Bs[lc + 1][lr + 64] = w1.y; Bs[lc + 2][lr + 64] = w1.z; Bs[lc + 3][lr + 64] = w1.w;
        __syncthreads();
#pragma unroll
        for (int kk = 0; kk < BKk; ++kk) {
            float av[8], bv[8];
            *(float4*)&av[0] = *(float4*)&As[kk][ty * 8];
            *(float4*)&av[4] = *(float4*)&As[kk][ty * 8 + 4];
            *(float4*)&bv[0] = *(float4*)&Bs[kk][tx * 8];
            *(float4*)&bv[4] = *(float4*)&Bs[kk][tx * 8 + 4];
#pragma unroll
            for (int i = 0; i < 8; ++i)
#pragma unroll
                for (int j = 0; j < 8; ++j)
                    acc[i][j] = fmaf(av[i], bv[j], acc[i][j]);
        }
    }

#pragma unroll
    for (int i = 0; i < 8; ++i) {
        long m = m0 + ty * 8 + i;
#pragma unroll
        for (int j = 0; j < 8; ++j) {
            int n = n0 + tx * 8 + j;
            float val = acc[i][j];
            if (bb1) val += bb1[n];
            if (bb2) val += bb2[n];
            if (bbn) val += bbn[(m >> 7) * (long)N + n];
            C[m * N + n] = val;
        }
    }
}

// ---------------------------------------------------------------------------
// LSTM recurrence, sentinel-dataflow exchange (no barrier, no flags).
// 32 blocks: d = bid>>4, slice s = bid&15. Yout is pre-filled with 0xFF bytes
// (NaN pattern 0xFFFFFFFF). h = og*tanh(c) is always finite, so "word !=
// 0xFFFFFFFF" <=> "written". Writers fire agent-scope relaxed write-through
// stores and never wait; readers poll their own h-words with agent-scope
// relaxed loads (bypass stale caches) until non-sentinel.
// G: [2][B*T][1536] precomputed input projections (+biases).
// Yout: [B][T][768] (fwd cols 0:384, bwd cols 384:768) = layer output.
// ---------------------------------------------------------------------------
__device__ __forceinline__ bool has_sent(unsigned long long v) {
    return ((unsigned)v == 0xFFFFFFFFu) || ((unsigned)(v >> 32) == 0xFFFFFFFFu);
}

__global__ __launch_bounds__(256, 1) void k_lstm(
    const float* __restrict__ G, const float* __restrict__ Whh, float* Yout)
{
    int bid = blockIdx.x;
    int d = bid >> 4;
    int s = bid & 15;
    int tid = threadIdx.x;
    int kq = tid >> 5;          // 0..7  (k-range of 48)
    int rg = tid & 31;          // 0..31 (3 rows each)
    int kq48 = kq * 48;

    __shared__ float hl[8 * 384];       // h_prev for all batches of this dir
    __shared__ float part[8 * 776];     // partials: [kq][b(stride 97)][row 0..95]

    // Load W slice into registers
    float W_[3][48];
    const float* Wd = Whh + (long)d * GATE * Ee;
#pragma unroll
    for (int r = 0; r < 3; ++r) {
        int rl = rg * 3 + r;
        int g = rl / 24, rr = rl % 24;
        const float* src = Wd + (long)(g * Ee + s * 24 + rr) * Ee + kq48;
#pragma unroll
        for (int k4 = 0; k4 < 12; ++k4) {
            float4 w = *(const float4*)&src[k4 * 4];
            W_[r][k4 * 4 + 0] = w.x;
            W_[r][k4 * 4 + 1] = w.y;
            W_[r][k4 * 4 + 2] = w.z;
            W_[r][k4 * 4 + 3] = w.w;
        }
    }

    float cst = 0.f;                  // cell state for update thread
    int ub = tid / 24, ur = tid % 24; // update thread -> (batch, h-row)
    bool upd = tid < 192;

    // G prefetch (one timestep ahead)
    float gpre[4];
    const float* gbase = G + ((long)d * 1024 + ub * Tt) * GATE + s * 24 + ur;
    {
        int tt0 = d ? 127 : 0;
        if (upd) {
#pragma unroll
            for (int g = 0; g < 4; ++g) gpre[g] = gbase[(long)tt0 * GATE + g * Ee];
        }
    }

    float4* hl4 = (float4*)hl;

    for (int it = 0; it < 128; ++it) {
        int tt = d ? (127 - it) : it;
        int tp = d ? (tt + 1) : (tt - 1);

        // stage h_{prev}: poll own words until non-sentinel (dataflow sync)
        if (it == 0) {
            float4 z4 = make_float4(0.f, 0.f, 0.f, 0.f);
#pragma unroll
            for (int ii = 0; ii < 3; ++ii) hl4[tid + 256 * ii] = z4;
        } else {
#pragma unroll
            for (int ii = 0; ii < 3; ++ii) {
                int i4 = tid + 256 * ii;       // 0..767
                int b = i4 / 96, k4 = i4 - b * 96;
                const unsigned long long* src = (const unsigned long long*)
                    &Yout[((long)(b * Tt + tp)) * Hh + d * Ee + k4 * 4];
                unsigned long long lo, hi;
                do {
                    lo = __hip_atomic_load(src, __ATOMIC_RELAXED, __HIP_MEMORY_SCOPE_AGENT);
                } while (has_sent(lo));
                do {
                    hi = __hip_atomic_load(src + 1, __ATOMIC_RELAXED, __HIP_MEMORY_SCOPE_AGENT);
                } while (has_sent(hi));
                float2 flo = __builtin_bit_cast(float2, lo);
                float2 fhi = __builtin_bit_cast(float2, hi);
                hl4[i4] = make_float4(flo.x, flo.y, fhi.x, fhi.y);
            }
        }
        __syncthreads();

        float acc[8][3];
#pragma unroll
        for (int b = 0; b < 8; ++b)
#pragma unroll
            for (int r = 0; r < 3; ++r) acc[b][r] = 0.f;

#pragma unroll
        for (int k4 = 0; k4 < 12; ++k4) {
#pragma unroll
            for (int b = 0; b < 8; ++b) {
                float4 hv = *(const float4*)&hl[b * 384 + kq48 + k4 * 4];
#pragma unroll
                for (int r = 0; r < 3; ++r) {
                    acc[b][r] = fmaf(W_[r][k4 * 4 + 0], hv.x, acc[b][r]);
                    acc[b][r] = fmaf(W_[r][k4 * 4 + 1], hv.y, acc[b][r]);
                    acc[b][r] = fmaf(W_[r][k4 * 4 + 2], hv.z, acc[b][r]);
                    acc[b][r] = fmaf(W_[r][k4 * 4 + 3], hv.w, acc[b][r]);
                }
            }
        }

        // write partials
#pragma unroll
        for (int b = 0; b < 8; ++b)
#pragma unroll
            for (int r = 0; r < 3; ++r)
                part[kq * 776 + b * 97 + rg * 3 + r] = acc[b][r];
        __syncthreads();

        if (upd) {
            float gt[4];
#pragma unroll
            for (int g = 0; g < 4; ++g) {
                int rl = g * 24 + ur;
                float sum = gpre[g];
#pragma unroll
                for (int q = 0; q < 8; ++q) sum += part[q * 776 + ub * 97 + rl];
                gt[g] = sum;
            }
            float ig = fast_sigmoid(gt[0]);
            float fg = fast_sigmoid(gt[1]);
            float gg = fast_tanh(gt[2]);
            float og = fast_sigmoid(gt[3]);
            cst = fg * cst + ig * gg;
            float h = og * fast_tanh(cst);
            // fire-and-forget write-through store to the coherence point
            __hip_atomic_store(&Yout[((long)(ub * Tt + tt)) * Hh + d * Ee + s * 24 + ur],
                               h, __ATOMIC_RELAXED, __HIP_MEMORY_SCOPE_AGENT);
            // prefetch next step's G (overlaps next staging poll)
            if (it != 127) {
                int ttn = d ? (tt - 1) : (tt + 1);
#pragma unroll
                for (int g = 0; g < 4; ++g) gpre[g] = gbase[(long)ttn * GATE + g * Ee];
            }
        }
    }
}

// ---------------------------------------------------------------------------
// Sentinel pre-fill: pattern-fill a float buffer with 0xFFFFFFFF
// ---------------------------------------------------------------------------
__global__ void k_fill_sent(float* __restrict__ p, int n4)
{
    int i = blockIdx.x * 256 + threadIdx.x;
    if (i < n4) {
        unsigned u = 0xFFFFFFFFu;
        float f = __builtin_bit_cast(float, u);
        ((float4*)p)[i] = make_float4(f, f, f, f);
    }
}

// ---------------------------------------------------------------------------
// p_term[b][n] = sum_k hs[b, qid[b], k] * W_p[n,k]
// grid (24, 8): blockIdx.y = b, blockIdx.x = 32-row chunk. 4 waves x 8 rows.
// ---------------------------------------------------------------------------
__global__ __launch_bounds__(256) void k_pterm(
    const float* __restrict__ hs, const int* __restrict__ qids,
    const float* __restrict__ Wp, float* __restrict__ pterm)
{
    int b = blockIdx.y;
    int chunk = blockIdx.x;
    int tid = threadIdx.x;
    int qid = qids[b];
    __shared__ float hp[Hh];
    for (int i = tid; i < Hh; i += 256) hp[i] = hs[((long)(b * Tt + qid)) * Hh + i];
    __syncthreads();
    int w = tid >> 6, lane = tid & 63;
#pragma unroll
    for (int r = 0; r < 8; ++r) {
        int n = chunk * 32 + w * 8 + r;
        const float* wrow = &Wp[(long)n * Hh];
        float p = 0.f;
#pragma unroll
        for (int k0 = 0; k0 < 3; ++k0) {
            int k = lane * 4 + k0 * 256;
            float4 wv = *(const float4*)&wrow[k];
            float4 hv = *(const float4*)&hp[k];
            p += wv.x * hv.x + wv.y * hv.y + wv.z * hv.z + wv.w * hv.w;
        }
#pragma unroll
        for (int o = 32; o; o >>= 1) p += __shfl_down(p, o);
        if (lane == 0) pterm[b * Hh + n] = p;
    }
}

// ---------------------------------------------------------------------------
// Fused attention per (b,t): scores -> softmax -> c -> logits.
// ---------------------------------------------------------------------------
__global__ __launch_bounds__(256) void k_attn(
    const float* __restrict__ hs, const float* __restrict__ A1, const float* __restrict__ A2,
    const float* __restrict__ v, const float* __restrict__ Wclf,
    float* __restrict__ a_mat, float* __restrict__ logits)
{
    int b = blockIdx.x >> 7, t = blockIdx.x & 127;
    int tid = threadIdx.x;
    long bt = (long)(b * Tt + t);

    __shared__ float a2r[Hh], vr[Hh], hsr[Hh], crow[Hh];
    __shared__ float sc[128], tmp[256], red2[2];

    for (int i = tid; i < Hh; i += 256) {
        a2r[i] = A2[bt * Hh + i];
        vr[i] = v[i];
        hsr[i] = hs[bt * Hh + i];
    }
    __syncthreads();

    // scores: 2 threads per s (each 384 of 768)
    {
        int sid = tid >> 1, half = tid & 1;
        float p = 0.f;
        const float* A1r = &A1[((long)(b * Tt + sid)) * Hh + half * 384];
        const float* a2h = &a2r[half * 384];
        const float* vh = &vr[half * 384];
        for (int k = 0; k < 384; k += 4) {
            float4 z = *(const float4*)&A1r[k];
            p += vh[k + 0] * fast_tanh(z.x + a2h[k + 0]);
            p += vh[k + 1] * fast_tanh(z.y + a2h[k + 1]);
            p += vh[k + 2] * fast_tanh(z.z + a2h[k + 2]);
            p += vh[k + 3] * fast_tanh(z.w + a2h[k + 3]);
        }
        tmp[tid] = p;
    }
    __syncthreads();
    if (tid < 128) sc[tid] = tmp[2 * tid] + tmp[2 * tid + 1];
    __syncthreads();

    // softmax over s
    if (tid < 64) {
        float m = fmaxf(sc[tid], sc[tid + 64]);
#pragma unroll
        for (int o = 32; o; o >>= 1) m = fmaxf(m, __shfl_down(m, o));
        if (tid == 0) red2[0] = m;
    }
    __syncthreads();
    float mx = red2[0];
    if (tid < 128) sc[tid] = __expf(sc[tid] - mx);
    __syncthreads();
    if (tid < 64) {
        float sm = sc[tid] + sc[tid + 64];
#pragma unroll
        for (int o = 32; o; o >>= 1) sm += __shfl_down(sm, o);
        if (tid == 0) red2[1] = sm;
    }
    __syncthreads();
    float inv = 1.f / red2[1];
    if (tid < 128) {
        sc[tid] *= inv;
        a_mat[bt * 128 + tid] = sc[tid];
    }
    __syncthreads();

    // c[b,t,:] = sum_s a_s * hs[b,s,:]
    float c0 = 0.f, c1 = 0.f, c2 = 0.f;
    for (int s2 = 0; s2 < 128; ++s2) {
        float as = sc[s2];
        const float* hrow = &hs[((long)(b * Tt + s2)) * Hh];
        c0 = fmaf(as, hrow[tid], c0);
        c1 = fmaf(as, hrow[tid + 256], c1);
        c2 = fmaf(as, hrow[tid + 512], c2);
    }
    crow[tid] = c0; crow[tid + 256] = c1; crow[tid + 512] = c2;
    __syncthreads();

    // logits[b,t,l] = [hs | c] . Wclf[l]
    for (int l = 0; l < Ll; ++l) {
        float p = 0.f;
        for (int h = tid; h < 2 * Hh; h += 256) {
            float u = (h < Hh) ? hsr[h] : crow[h - Hh];
            p = fmaf(u, Wclf[l * 2 * Hh + h], p);
        }
#pragma unroll
        for (int o = 32; o; o >>= 1) p += __shfl_down(p, o);
        if ((tid & 63) == 0) tmp[tid >> 6] = p;
        __syncthreads();
        if (tid == 0) logits[bt * Ll + l] = tmp[0] + tmp[1] + tmp[2] + tmp[3];
        __syncthreads();
    }
}

// ---------------------------------------------------------------------------
// a_t[b][s] = (sum_t a[b,t,s]) / (sum_s sum_t a[b,t,s])
// ---------------------------------------------------------------------------
__global__ void k_norm(const float* __restrict__ a_mat, float* __restrict__ a_t)
{
    int b = blockIdx.x;
    int s = threadIdx.x; // 128
    float sum = 0.f;
    for (int t = 0; t < Tt; ++t) sum += a_mat[((long)(b * Tt + t)) * 128 + s];
    __shared__ float pool[128];
    __shared__ float tot;
    pool[s] = sum;
    __syncthreads();
    if (s < 64) {
        float v2 = pool[s] + pool[s + 64];
#pragma unroll
        for (int o = 32; o; o >>= 1) v2 += __shfl_down(v2, o);
        if (s == 0) tot = v2;
    }
    __syncthreads();
    float tv = tot;
    a_t[b * 128 + s] = (tv != 0.f) ? pool[s] / tv : 0.f;
}

// ---------------------------------------------------------------------------
// Viterbi (L=9). One block. Strict-> argmax to match jnp.argmax first-max.
// ---------------------------------------------------------------------------
__global__ void k_viterbi(const float* __restrict__ logits, const float* __restrict__ trans,
                          const float* __restrict__ start, const float* __restrict__ endw,
                          float* __restrict__ out)
{
    __shared__ float sc[2][72];
    __shared__ unsigned char ptrs[127][72];
    __shared__ unsigned char tags[8][128];
    int tid = threadIdx.x;
    int b = tid / 9, j = tid % 9;
    bool act = tid < 72;
    if (act) sc[0][b * 9 + j] = start[j] + logits[(b * Tt + 0) * Ll + j];
    __syncthreads();
    for (int t = 1; t < Tt; ++t) {
        int cur = t & 1, prv = cur ^ 1;
        if (act) {
            float best = -1e30f; int bi = 0;
#pragma unroll
            for (int i = 0; i < 9; ++i) {
                float vv = sc[prv][b * 9 + i] + trans[i * 9 + j];
                if (vv > best) { best = vv; bi = i; }
            }
            sc[cur][b * 9 + j] = best + logits[(b * Tt + t) * Ll + j];
            ptrs[t - 1][b * 9 + j] = (unsigned char)bi;
        }
        __syncthreads();
    }
    if (act && j == 0) {
        float best = -1e30f; int bj = 0;
#pragma unroll
        for (int jj = 0; jj < 9; ++jj) {
            float vv = sc[1][b * 9 + jj] + endw[jj];
            if (vv > best) { best = vv; bj = jj; }
        }
        int tg = bj;
        tags[b][127] = (unsigned char)tg;
        for (int t = 127; t >= 1; --t) {
            tg = ptrs[t - 1][b * 9 + tg];
            tags[b][t - 1] = (unsigned char)tg;
        }
    }
    __syncthreads();
    for (int i = tid; i < Bq * Tt * Ll; i += blockDim.x) {
        int l = i % 9;
        int btx = i / 9;
        int tt2 = btx % Tt;
        int bb = btx / Tt;
        out[i] = (tags[bb][tt2] == l) ? 10.f : -1.f;
    }
}

// ---------------------------------------------------------------------------
extern "C" void kernel_launch(void* const* d_in, const int* in_sizes, int n_in,
                              void* d_out, int out_size, void* d_ws, size_t ws_size,
                              hipStream_t stream)
{
    const float* embeds   = (const float*)d_in[0];
    const int*   qids     = (const int*)d_in[1];
    const float* w_ih_l0  = (const float*)d_in[2];
    const float* w_ih_rest= (const float*)d_in[3];
    const float* w_hh     = (const float*)d_in[4];
    const float* b_ih     = (const float*)d_in[5];
    const float* b_hh     = (const float*)d_in[6];
    const float* W_H      = (const float*)d_in[7];
    const float* W_p      = (const float*)d_in[8];
    const float* W_h      = (const float*)d_in[9];
    const float* vvec     = (const float*)d_in[10];
    const float* W_clf    = (const float*)d_in[11];
    const float* trans    = (const float*)d_in[12];
    const float* cstart   = (const float*)d_in[13];
    const float* cend     = (const float*)d_in[14];

    float* out = (float*)d_out;
    float* vit_out = out;                          // 8*128*9   = 9216
    float* hs      = out + 9216;                   // 8*128*768 = 786432
    float* a_t     = out + 9216 + 786432;          // 8*128     = 1024

    // Workspace overlay:
    //  phase A (LSTM):   G [3145728] | Y0 [786432] | Y1 [786432]
    //  phase B (attn):   A1,A2,pterm,a_mat,logits all inside G's region
    float* ws = (float*)d_ws;
    float* G      = ws;                  // 3145728 floats
    float* Y0     = ws + 3145728;        // 786432
    float* Y1     = Y0 + 786432;         // 786432
    float* A1     = ws;                  // reuses G (dead after last lstm)
    float* A2     = A1 + 786432;
    float* pterm  = A2 + 786432;         // 6144
    float* a_mat  = pterm + 6144;        // 131072
    float* logits = a_mat + 131072;      // 9216  (ends well inside G region)

    dim3 blk(256);
    const int n4 = 786432 / 4;           // float4 count per Y buffer
    const int fillgrid = (n4 + 255) / 256;

    // Sentinel pre-fill of the three exchange buffers (0xFFFFFFFF = NaN).
    k_fill_sent<<<dim3(fillgrid), blk, 0, stream>>>(Y0, n4);
    k_fill_sent<<<dim3(fillgrid), blk, 0, stream>>>(Y1, n4);
    k_fill_sent<<<dim3(fillgrid), blk, 0, stream>>>(hs, n4);

    // ---- Layer 0 ----
    k_gemm<<<dim3(GATE / BN, 1024 / BM, 2), blk, 0, stream>>>(
        embeds, w_ih_l0, G, 1024, GATE, Ee,
        0L, (long)GATE * Ee, (long)1024 * GATE,
        b_ih, b_hh, (long)GATE, nullptr);
    k_lstm<<<dim3(32), blk, 0, stream>>>(G, w_hh, Y0);

    // ---- Layer 1 ----
    k_gemm<<<dim3(GATE / BN, 1024 / BM, 2), blk, 0, stream>>>(
        Y0, w_ih_rest, G, 1024, GATE, Hh,
        0L, (long)GATE * Hh, (long)1024 * GATE,
        b_ih + 2 * GATE, b_hh + 2 * GATE, (long)GATE, nullptr);
    k_lstm<<<dim3(32), blk, 0, stream>>>(G, w_hh + (long)2 * GATE * Ee, Y1);

    // ---- Layer 2 ----
    k_gemm<<<dim3(GATE / BN, 1024 / BM, 2), blk, 0, stream>>>(
        Y1, w_ih_rest + (long)2 * GATE * Hh, G, 1024, GATE, Hh,
        0L, (long)GATE * Hh, (long)1024 * GATE,
        b_ih + 4 * GATE, b_hh + 4 * GATE, (long)GATE, nullptr);
    k_lstm<<<dim3(32), blk, 0, stream>>>(G, w_hh + (long)4 * GATE * Ee, hs);

    // ---- Attention precompute ----
    k_pterm<<<dim3(24, 8), blk, 0, stream>>>(hs, qids, W_p, pterm);
    k_gemm<<<dim3(Hh / BN, 1024 / BM, 1), blk, 0, stream>>>(
        hs, W_H, A1, 1024, Hh, Hh, 0L, 0L, 0L, nullptr, nullptr, 0L, nullptr);
    k_gemm<<<dim3(Hh / BN, 1024 / BM, 1), blk, 0, stream>>>(
        hs, W_h, A2, 1024, Hh, Hh, 0L, 0L, 0L, nullptr, nullptr, 0L, pterm);

    // ---- Fused attention + logits ----
    k_attn<<<dim3(1024), blk, 0, stream>>>(hs, A1, A2, vvec, W_clf, a_mat, logits);

    // ---- Pooled attention norm -> a_t ----
    k_norm<<<dim3(8), dim3(128), 0, stream>>>(a_mat, a_t);

    // ---- Viterbi -> vit_logits ----
    k_viterbi<<<dim3(1), dim3(128), 0, stream>>>(logits, trans, cstart, cend, vit_out);
}